// Round 1
// baseline (1218.637 us; speedup 1.0000x reference)
//
#include <hip/hip_runtime.h>

// ---- problem constants ----
#define B_      64
#define NSEQ    482
#define DIM     512
#define HEADS_  8
#define HD      64
#define QKV3    1536
#define NPAD    512            // padded sequence length for attention tensors
#define MROWS   (B_ * NSEQ)    // 30848 = 241 * 128
#define SROW    504            // padded bf16 score-row length (bank-friendly, 16B-aligned)

typedef __bf16 v8bf __attribute__((ext_vector_type(8)));
typedef float  v4f  __attribute__((ext_vector_type(4)));

__device__ __forceinline__ unsigned short f2bf(float f) {
    unsigned u = __float_as_uint(f);
    u += 0x7fffu + ((u >> 16) & 1u);           // RNE
    return (unsigned short)(u >> 16);
}
__device__ __forceinline__ float bf2f(unsigned short h) {
    return __uint_as_float(((unsigned)h) << 16);
}

// ---------------- conversions ----------------
__global__ void k_cvt(const float* __restrict__ s, unsigned short* __restrict__ d, int n4) {
    int i = blockIdx.x * 256 + threadIdx.x;
    if (i < n4) {
        float4 v = ((const float4*)s)[i];
        ushort4 o;
        o.x = f2bf(v.x); o.y = f2bf(v.y); o.z = f2bf(v.z); o.w = f2bf(v.w);
        ((ushort4*)d)[i] = o;
    }
}

__global__ void k_cvtabs(const float* __restrict__ s, unsigned short* __restrict__ d,
                         unsigned short* __restrict__ da, int n4) {
    int i = blockIdx.x * 256 + threadIdx.x;
    if (i < n4) {
        float4 v = ((const float4*)s)[i];
        ushort4 o, oa;
        o.x = f2bf(v.x); o.y = f2bf(v.y); o.z = f2bf(v.z); o.w = f2bf(v.w);
        oa.x = f2bf(fabsf(v.x)); oa.y = f2bf(fabsf(v.y));
        oa.z = f2bf(fabsf(v.z)); oa.w = f2bf(fabsf(v.w));
        ((ushort4*)d)[i] = o;
        ((ushort4*)da)[i] = oa;
    }
}

// ---------------- updated gate (fp32, exact) ----------------
__global__ void k_upd(const float* __restrict__ mask, float* __restrict__ upd) {
    int row = blockIdx.x * 4 + (threadIdx.x >> 6);
    int lane = threadIdx.x & 63;
    int i = row % NSEQ;
    float r;
    if (i == 0) {
        r = 1.f;
    } else {
        const float* p = mask + (size_t)row * DIM;
        float s = 0.f;
        #pragma unroll
        for (int j = 0; j < 8; j++) s += p[lane + 64 * j];
        #pragma unroll
        for (int off = 32; off; off >>= 1) s += __shfl_xor(s, off);
        r = (s > 0.f) ? 1.f : 0.f;     // mean>0 <=> sum>0
    }
    if (lane == 0) upd[row] = r;
}

// ---------------- generic bf16 GEMM: C[M,N] = A[M,K] @ B[N,K]^T (+bias) ----------------
// 128x128 tile, 4 waves (2x2), 4x4 16x16x32 MFMA micro-tiles. M from gridDim.y.
__global__ __launch_bounds__(256, 2) void k_gemm(const unsigned short* __restrict__ A,
                                                 const unsigned short* __restrict__ Bw,
                                                 unsigned short* __restrict__ Cb,
                                                 float* __restrict__ Cf,
                                                 const float* __restrict__ bias,
                                                 int N, int K) {
    __shared__ unsigned short As[128 * 40];   // 32 k + 8 pad -> 2-way (free) LDS banks
    __shared__ unsigned short Bs[128 * 40];
    int tid = threadIdx.x;
    int lane = tid & 63, w = tid >> 6;
    int wm = w & 1, wn = w >> 1;
    int quad = lane >> 4, m16 = lane & 15;
    int m0 = blockIdx.y * 128, n0 = blockIdx.x * 128;

    v4f acc[4][4];
    #pragma unroll
    for (int i = 0; i < 4; i++)
        #pragma unroll
        for (int j = 0; j < 4; j++) acc[i][j] = (v4f){0.f, 0.f, 0.f, 0.f};

    for (int k0 = 0; k0 < K; k0 += 32) {
        #pragma unroll
        for (int rr = 0; rr < 2; rr++) {
            int cid = tid + rr * 256;
            int row = cid >> 2, kc = cid & 3;
            *(int4*)&As[row * 40 + kc * 8] =
                *(const int4*)&A[(size_t)(m0 + row) * K + k0 + kc * 8];
            *(int4*)&Bs[row * 40 + kc * 8] =
                *(const int4*)&Bw[(size_t)(n0 + row) * K + k0 + kc * 8];
        }
        __syncthreads();
        v8bf af[4], bf[4];
        #pragma unroll
        for (int i = 0; i < 4; i++)
            af[i] = *(const v8bf*)&As[(wm * 64 + i * 16 + m16) * 40 + quad * 8];
        #pragma unroll
        for (int j = 0; j < 4; j++)
            bf[j] = *(const v8bf*)&Bs[(wn * 64 + j * 16 + m16) * 40 + quad * 8];
        #pragma unroll
        for (int i = 0; i < 4; i++)
            #pragma unroll
            for (int j = 0; j < 4; j++)
                acc[i][j] = __builtin_amdgcn_mfma_f32_16x16x32_bf16(af[i], bf[j], acc[i][j], 0, 0, 0);
        __syncthreads();
    }

    // epilogue: D[row=quad*4+r][col=m16]  (verified C/D layout)
    #pragma unroll
    for (int j = 0; j < 4; j++) {
        int col = n0 + wn * 64 + j * 16 + m16;
        float bi = bias ? bias[col] : 0.f;
        #pragma unroll
        for (int i = 0; i < 4; i++) {
            int rowb = m0 + wm * 64 + i * 16 + quad * 4;
            #pragma unroll
            for (int r = 0; r < 4; r++) {
                float v = acc[i][j][r] + bi;
                size_t off = (size_t)(rowb + r) * N + col;
                if (Cf) Cf[off] = v;
                else    Cb[off] = f2bf(v);
            }
        }
    }
}

// ---------------- per-(b,col) max over n of qkv_m -> 1/(1e-6+max) ----------------
__global__ void k_colmax(const unsigned short* __restrict__ qm, float* __restrict__ invsc) {
    int b = blockIdx.x;
    int c = blockIdx.y * 256 + threadIdx.x;
    const unsigned short* p = qm + (size_t)b * NSEQ * QKV3 + c;
    float mx = -1e30f;
    for (int i = 0; i < NSEQ; i++) mx = fmaxf(mx, bf2f(p[(size_t)i * QKV3]));
    invsc[b * QKV3 + c] = 1.f / (1e-6f + mx);
}

// ---------------- build attention operands ----------------
// QQ = q*qm_norm*SCALE, KK = k*km_norm (row-major [b,h,i,d]); VVt = v*vm_norm, VMt = vm_norm
// (transposed [b,h,d,i], i padded to 512 with zeros -> uniform K-loop in attention).
__global__ __launch_bounds__(256) void k_build(const unsigned short* __restrict__ qkv,
                                               const unsigned short* __restrict__ qm,
                                               const float* __restrict__ invsc,
                                               unsigned short* __restrict__ QQ,
                                               unsigned short* __restrict__ KK,
                                               unsigned short* __restrict__ VVt,
                                               unsigned short* __restrict__ VMt) {
    __shared__ unsigned short tv[64][72];
    __shared__ unsigned short tm[64][72];
    int tid = threadIdx.x;
    int dd = tid & 63, il = tid >> 6;
    int it = blockIdx.x, h = blockIdx.y, b = blockIdx.z;
    int i0 = it * 64;
    size_t bh = (size_t)(b * HEADS_ + h);
    int c = h * HD + dd;
    float invq = invsc[b * QKV3 + c] * 0.125f;   // fold softmax scale 1/sqrt(64)
    float invk = invsc[b * QKV3 + 512 + c];
    float invv = invsc[b * QKV3 + 1024 + c];
    #pragma unroll 4
    for (int p = 0; p < 16; p++) {
        int li = p * 4 + il;
        int i = i0 + li;
        unsigned short oq = 0, ok = 0, ov = 0, om = 0;
        if (i < NSEQ) {
            size_t base = ((size_t)(b * NSEQ + i)) * QKV3 + c;
            float q  = bf2f(qkv[base]),        qv = bf2f(qm[base]);
            float kk = bf2f(qkv[base + 512]),  kv = bf2f(qm[base + 512]);
            float vv = bf2f(qkv[base + 1024]), vm = bf2f(qm[base + 1024]);
            oq = f2bf(q * qv * invq);
            ok = f2bf(kk * kv * invk);
            float vmn = vm * invv;
            ov = f2bf(vv * vmn);
            om = f2bf(vmn);
        }
        QQ[(bh * NPAD + i) * HD + dd] = oq;
        KK[(bh * NPAD + i) * HD + dd] = ok;
        tv[li][dd] = ov;
        tm[li][dd] = om;
    }
    __syncthreads();
    #pragma unroll 4
    for (int p = 0; p < 16; p++) {
        int dr = p * 4 + il;
        VVt[(bh * HD + dr) * NPAD + i0 + dd] = tv[dd][dr];
        VMt[(bh * HD + dr) * NPAD + i0 + dd] = tm[dd][dr];
    }
}

// ---------------- fused attention: S=QK^T -> softmax -> (P@VV, P@VM), gated by `updated` ----
// block = 4 waves, 64 queries of one (b,h); wave owns 16 query rows.
// Scores kept as bf16 rows (SROW=504) in 64KB LDS; softmax converts S->P in place
// (wave-ordered LDS ops make the in-place rewrite safe). Phase-2 K-window [480,512)
// reads 8 bf16 past the row end; the matching VVt/VMt columns 496..511 are zero, so
// those products vanish (row 63 overflow lands in an explicitly zeroed 8-entry pad).
__global__ __launch_bounds__(256, 2) void k_attn(const unsigned short* __restrict__ QQ,
                                                 const unsigned short* __restrict__ KK,
                                                 const unsigned short* __restrict__ VVt,
                                                 const unsigned short* __restrict__ VMt,
                                                 const float* __restrict__ upd,
                                                 float* __restrict__ OUT1,
                                                 float* __restrict__ M1) {
    __shared__ __align__(16) unsigned short S[4 * 16 * SROW + 8];
    int tid = threadIdx.x;
    int w = tid >> 6, lane = tid & 63;
    int quad = lane >> 4, m16 = lane & 15;
    int b = blockIdx.z, h = blockIdx.y;
    int q0 = blockIdx.x * 64;
    size_t bh = (size_t)(b * HEADS_ + h);
    if (tid < 8) S[4 * 16 * SROW + tid] = 0;

    // Q fragments (A-layout: A[m=lane&15][k=quad*8+j]), loaded once
    int qrow = q0 + w * 16 + m16;
    const unsigned short* qbase = &QQ[(bh * NPAD + qrow) * HD];
    v8bf aq0 = *(const v8bf*)&qbase[quad * 8];
    v8bf aq1 = *(const v8bf*)&qbase[32 + quad * 8];

    unsigned short* Sw = S + w * 16 * SROW;

    // phase 1: scores for this wave's 16 rows over 31 key-tiles of 16
    for (int kt = 0; kt < 31; ++kt) {
        const unsigned short* kbase = &KK[(bh * NPAD + kt * 16 + m16) * HD];
        v8bf b0 = *(const v8bf*)&kbase[quad * 8];
        v8bf b1 = *(const v8bf*)&kbase[32 + quad * 8];
        v4f acc = (v4f){0.f, 0.f, 0.f, 0.f};
        acc = __builtin_amdgcn_mfma_f32_16x16x32_bf16(aq0, b0, acc, 0, 0, 0);
        acc = __builtin_amdgcn_mfma_f32_16x16x32_bf16(aq1, b1, acc, 0, 0, 0);
        int col = kt * 16 + m16;
        #pragma unroll
        for (int r = 0; r < 4; r++) Sw[(quad * 4 + r) * SROW + col] = f2bf(acc[r]);
    }
    __syncthreads();

    // softmax per row (fp32), write P (bf16) in place
    for (int r = 0; r < 16; r++) {
        unsigned short* Sr = Sw + r * SROW;
        float v[8];
        #pragma unroll
        for (int j = 0; j < 8; j++) {
            int k = lane + 64 * j;
            v[j] = (k < NSEQ) ? bf2f(Sr[k]) : -1e30f;
        }
        float mx = v[0];
        #pragma unroll
        for (int j = 1; j < 8; j++) mx = fmaxf(mx, v[j]);
        #pragma unroll
        for (int off = 32; off; off >>= 1) mx = fmaxf(mx, __shfl_xor(mx, off));
        float e[8];
        float sum = 0.f;
        #pragma unroll
        for (int j = 0; j < 8; j++) {
            int k = lane + 64 * j;
            float ev = (k < NSEQ) ? __expf(v[j] - mx) : 0.f;
            e[j] = ev; sum += ev;
        }
        #pragma unroll
        for (int off = 32; off; off >>= 1) sum += __shfl_xor(sum, off);
        float inv = 1.f / sum;
        #pragma unroll
        for (int j = 0; j < 8; j++) {
            int k = lane + 64 * j;
            if (k < SROW) Sr[k] = (k < NSEQ) ? f2bf(e[j] * inv) : 0;
        }
    }
    __syncthreads();   // makes the cross-row overflow reads deterministic

    // phase 2: O = P@VV, M = P@VM (shared A fragment)
    for (int dt = 0; dt < 4; ++dt) {
        const unsigned short* vb = &VVt[(bh * HD + dt * 16 + m16) * NPAD];
        const unsigned short* mb = &VMt[(bh * HD + dt * 16 + m16) * NPAD];
        v4f ao = (v4f){0.f, 0.f, 0.f, 0.f};
        v4f am = (v4f){0.f, 0.f, 0.f, 0.f};
        #pragma unroll 4
        for (int ks = 0; ks < 16; ++ks) {
            v8bf a  = *(const v8bf*)&Sw[m16 * SROW + ks * 32 + quad * 8];
            v8bf bo = *(const v8bf*)&vb[ks * 32 + quad * 8];
            v8bf bm = *(const v8bf*)&mb[ks * 32 + quad * 8];
            ao = __builtin_amdgcn_mfma_f32_16x16x32_bf16(a, bo, ao, 0, 0, 0);
            am = __builtin_amdgcn_mfma_f32_16x16x32_bf16(a, bm, am, 0, 0, 0);
        }
        #pragma unroll
        for (int r = 0; r < 4; r++) {
            int iq = q0 + w * 16 + quad * 4 + r;
            if (iq < NSEQ) {
                float u = upd[b * NSEQ + iq];
                size_t off = ((size_t)(b * NSEQ + iq)) * DIM + h * HD + dt * 16 + m16;
                OUT1[off] = ao[r] * u;
                M1[off]   = am[r] * u;
            }
        }
    }
}

// ---------------- overlap blending + row means (fp32), outputs bf16 GEMM inputs --------
__global__ __launch_bounds__(256) void k_blend(const float* __restrict__ O1,
                                               const float* __restrict__ Mm,
                                               const float* __restrict__ upd,
                                               unsigned short* __restrict__ O2,
                                               unsigned short* __restrict__ M2,
                                               float* __restrict__ mm) {
    int blk = blockIdx.x;
    int b = blk / NSEQ, i = blk - b * NSEQ;
    int tid = threadIdx.x;
    size_t rb = (size_t)blk * DIM;
    int ns = 0;
    size_t src[4];
    float wgt = 0.f;
    if (i >= 1) {
        wgt = 0.25f * (1.f - upd[blk]);
        if (wgt != 0.f) {
            if (i <= 256) {                       // grid row <- pooled(tail), padded pool
                int g = i - 1, gy = g >> 4, gx = g & 15;
                #pragma unroll
                for (int dy = 0; dy < 2; dy++)
                    #pragma unroll
                    for (int dx = 0; dx < 2; dx++) {
                        int sy = gy - 1 + dy, sx = gx - 1 + dx;
                        if (sy >= 0 && sy < 15 && sx >= 0 && sx < 15)
                            src[ns++] = ((size_t)(b * NSEQ + 257 + sy * 15 + sx)) * DIM;
                    }
            } else {                              // tail row <- pooled(grid), stride-1 2x2
                int t = i - 257, ty = t / 15, tx = t - ty * 15;
                #pragma unroll
                for (int dy = 0; dy < 2; dy++)
                    #pragma unroll
                    for (int dx = 0; dx < 2; dx++)
                        src[ns++] = ((size_t)(b * NSEQ + 1 + (ty + dy) * 16 + (tx + dx))) * DIM;
            }
        }
    }
    float msum = 0.f;
    for (int c = tid; c < DIM; c += 256) {
        float o = O1[rb + c], m = Mm[rb + c];
        float ao = 0.f, am = 0.f;
        for (int s = 0; s < ns; s++) { ao += O1[src[s] + c]; am += Mm[src[s] + c]; }
        o += wgt * ao;
        m += wgt * am;
        O2[rb + c] = f2bf(o);
        M2[rb + c] = f2bf(m);
        msum += m;
    }
    #pragma unroll
    for (int off = 32; off; off >>= 1) msum += __shfl_xor(msum, off);
    __shared__ float red[4];
    if ((tid & 63) == 0) red[tid >> 6] = msum;
    __syncthreads();
    if (tid == 0 && i >= 1)
        mm[b * 481 + i - 1] = (red[0] + red[1] + red[2] + red[3]) * (1.f / 512.f);
}

// ---------------- nearest-neighbor inter map ----------------
__global__ void k_inter(const float* __restrict__ mm, float* __restrict__ dst) {
    int idx = blockIdx.x * 256 + threadIdx.x;
    int b = idx >> 16, rem = idx & 65535;
    int y = rem >> 8, x = rem & 255;
    const float* mb = mm + b * 481;
    float v = mb[((y >> 4) << 4) + (x >> 4)];
    if (y >= 8 && y < 248 && x >= 8 && x < 248)
        v = 0.5f * (v + mb[256 + ((y - 8) >> 4) * 15 + ((x - 8) >> 4)]);
    dst[idx] = v;
}

// ---------------- driver ----------------
extern "C" void kernel_launch(void* const* d_in, const int* in_sizes, int n_in,
                              void* d_out, int out_size, void* d_ws, size_t ws_size,
                              hipStream_t stream) {
    const float* x    = (const float*)d_in[0];
    const float* mask = (const float*)d_in[1];
    const float* Wqkv = (const float*)d_in[2];
    const float* Wout = (const float*)d_in[3];
    const float* bout = (const float*)d_in[4];
    float* out = (float*)d_out;

    char* ws = (char*)d_ws;
    size_t o = 0;
    auto alloc = [&](size_t bytes) -> char* {
        char* r = ws + o;
        o += (bytes + 255) & ~(size_t)255;
        return r;
    };
    unsigned short* xb    = (unsigned short*)alloc((size_t)MROWS * DIM * 2);
    unsigned short* maskb = (unsigned short*)alloc((size_t)MROWS * DIM * 2);
    unsigned short* Wb    = (unsigned short*)alloc((size_t)QKV3 * DIM * 2);
    unsigned short* Wab   = (unsigned short*)alloc((size_t)QKV3 * DIM * 2);
    unsigned short* Wob   = (unsigned short*)alloc((size_t)DIM * DIM * 2);
    unsigned short* Woab  = (unsigned short*)alloc((size_t)DIM * DIM * 2);
    unsigned short* qkvb  = (unsigned short*)alloc((size_t)MROWS * QKV3 * 2);
    unsigned short* qkvmb = (unsigned short*)alloc((size_t)MROWS * QKV3 * 2);
    float* upd  = (float*)alloc((size_t)MROWS * 4);
    float* invs = (float*)alloc((size_t)B_ * QKV3 * 4);
    float* mm   = (float*)alloc((size_t)B_ * 481 * 4);
    unsigned short* QQ  = (unsigned short*)alloc((size_t)B_ * HEADS_ * NPAD * HD * 2);
    unsigned short* KK  = (unsigned short*)alloc((size_t)B_ * HEADS_ * NPAD * HD * 2);
    unsigned short* VVt = (unsigned short*)alloc((size_t)B_ * HEADS_ * NPAD * HD * 2);
    unsigned short* VMt = (unsigned short*)alloc((size_t)B_ * HEADS_ * NPAD * HD * 2);
    // aliases over dead buffers (qkv dead after k_build; xb/maskb dead after GEMM1)
    float* OUT1 = (float*)qkvb;
    float* M1p  = (float*)qkvmb;
    unsigned short* O2 = xb;
    unsigned short* M2 = maskb;

    // conversions + gate
    k_cvt<<<(MROWS * DIM / 4) / 256, 256, 0, stream>>>(x, xb, MROWS * DIM / 4);
    k_cvt<<<(MROWS * DIM / 4) / 256, 256, 0, stream>>>(mask, maskb, MROWS * DIM / 4);
    k_cvtabs<<<(QKV3 * DIM / 4) / 256, 256, 0, stream>>>(Wqkv, Wb, Wab, QKV3 * DIM / 4);
    k_cvtabs<<<(DIM * DIM / 4) / 256, 256, 0, stream>>>(Wout, Wob, Woab, DIM * DIM / 4);
    k_upd<<<MROWS / 4, 256, 0, stream>>>(mask, upd);

    // qkv projections (bf16 out)
    dim3 g1(QKV3 / 128, MROWS / 128);
    k_gemm<<<g1, 256, 0, stream>>>(xb, Wb, qkvb, nullptr, nullptr, QKV3, DIM);
    k_gemm<<<g1, 256, 0, stream>>>(maskb, Wab, qkvmb, nullptr, nullptr, QKV3, DIM);

    // normalization scales + operand build
    k_colmax<<<dim3(B_, QKV3 / 256), 256, 0, stream>>>(qkvmb, invs);
    k_build<<<dim3(8, HEADS_, B_), 256, 0, stream>>>(qkvb, qkvmb, invs, QQ, KK, VVt, VMt);

    // fused attention (writes gated OUT1 / M1)
    k_attn<<<dim3(8, HEADS_, B_), 256, 0, stream>>>(QQ, KK, VVt, VMt, upd, OUT1, M1p);

    // overlap blend + row means, inter map
    k_blend<<<MROWS, 256, 0, stream>>>(OUT1, M1p, upd, O2, M2, mm);
    k_inter<<<(B_ * 65536) / 256, 256, 0, stream>>>(mm, out + (size_t)2 * MROWS * DIM);

    // output projections (f32 out into d_out)
    dim3 g2(DIM / 128, MROWS / 128);
    k_gemm<<<g2, 256, 0, stream>>>(O2, Wob, nullptr, out, bout, DIM, DIM);
    k_gemm<<<g2, 256, 0, stream>>>(M2, Woab, nullptr, out + (size_t)MROWS * DIM, nullptr, DIM, DIM);
}

// Round 2
// 1088.183 us; speedup vs baseline: 1.1199x; 1.1199x over previous
//
#include <hip/hip_runtime.h>

// ---- problem constants ----
#define B_      64
#define NSEQ    482
#define DIM     512
#define HEADS_  8
#define HD      64
#define QKV3    1536
#define NPAD    512            // padded sequence length for attention tensors
#define MROWS   (B_ * NSEQ)    // 30848 = 241 * 128

typedef __bf16 v8bf __attribute__((ext_vector_type(8)));
typedef float  v4f  __attribute__((ext_vector_type(4)));

__device__ __forceinline__ unsigned short f2bf(float f) {
    unsigned u = __float_as_uint(f);
    u += 0x7fffu + ((u >> 16) & 1u);           // RNE
    return (unsigned short)(u >> 16);
}
__device__ __forceinline__ float bf2f(unsigned short h) {
    return __uint_as_float(((unsigned)h) << 16);
}

// ---------------- conversions ----------------
__global__ void k_cvt(const float* __restrict__ s, unsigned short* __restrict__ d, int n4) {
    int i = blockIdx.x * 256 + threadIdx.x;
    if (i < n4) {
        float4 v = ((const float4*)s)[i];
        ushort4 o;
        o.x = f2bf(v.x); o.y = f2bf(v.y); o.z = f2bf(v.z); o.w = f2bf(v.w);
        ((ushort4*)d)[i] = o;
    }
}

__global__ void k_cvtabs(const float* __restrict__ s, unsigned short* __restrict__ d,
                         unsigned short* __restrict__ da, int n4) {
    int i = blockIdx.x * 256 + threadIdx.x;
    if (i < n4) {
        float4 v = ((const float4*)s)[i];
        ushort4 o, oa;
        o.x = f2bf(v.x); o.y = f2bf(v.y); o.z = f2bf(v.z); o.w = f2bf(v.w);
        oa.x = f2bf(fabsf(v.x)); oa.y = f2bf(fabsf(v.y));
        oa.z = f2bf(fabsf(v.z)); oa.w = f2bf(fabsf(v.w));
        ((ushort4*)d)[i] = o;
        ((ushort4*)da)[i] = oa;
    }
}

// ---------------- updated gate (fp32, exact) ----------------
__global__ void k_upd(const float* __restrict__ mask, float* __restrict__ upd) {
    int row = blockIdx.x * 4 + (threadIdx.x >> 6);
    int lane = threadIdx.x & 63;
    int i = row % NSEQ;
    float r;
    if (i == 0) {
        r = 1.f;
    } else {
        const float* p = mask + (size_t)row * DIM;
        float s = 0.f;
        #pragma unroll
        for (int j = 0; j < 8; j++) s += p[lane + 64 * j];
        #pragma unroll
        for (int off = 32; off; off >>= 1) s += __shfl_xor(s, off);
        r = (s > 0.f) ? 1.f : 0.f;     // mean>0 <=> sum>0
    }
    if (lane == 0) upd[row] = r;
}

// ---------------- generic bf16 GEMM: C[M,N] = A[M,K] @ B[N,K]^T (+bias) ----------------
// 128x128 tile, 4 waves (2x2), 4x4 16x16x32 MFMA micro-tiles. M from gridDim.y.
__global__ __launch_bounds__(256, 2) void k_gemm(const unsigned short* __restrict__ A,
                                                 const unsigned short* __restrict__ Bw,
                                                 unsigned short* __restrict__ Cb,
                                                 float* __restrict__ Cf,
                                                 const float* __restrict__ bias,
                                                 int N, int K) {
    __shared__ unsigned short As[128 * 40];   // 32 k + 8 pad -> 2-way (free) LDS banks
    __shared__ unsigned short Bs[128 * 40];
    int tid = threadIdx.x;
    int lane = tid & 63, w = tid >> 6;
    int wm = w & 1, wn = w >> 1;
    int quad = lane >> 4, m16 = lane & 15;
    int m0 = blockIdx.y * 128, n0 = blockIdx.x * 128;

    v4f acc[4][4];
    #pragma unroll
    for (int i = 0; i < 4; i++)
        #pragma unroll
        for (int j = 0; j < 4; j++) acc[i][j] = (v4f){0.f, 0.f, 0.f, 0.f};

    for (int k0 = 0; k0 < K; k0 += 32) {
        #pragma unroll
        for (int rr = 0; rr < 2; rr++) {
            int cid = tid + rr * 256;
            int row = cid >> 2, kc = cid & 3;
            *(int4*)&As[row * 40 + kc * 8] =
                *(const int4*)&A[(size_t)(m0 + row) * K + k0 + kc * 8];
            *(int4*)&Bs[row * 40 + kc * 8] =
                *(const int4*)&Bw[(size_t)(n0 + row) * K + k0 + kc * 8];
        }
        __syncthreads();
        v8bf af[4], bf[4];
        #pragma unroll
        for (int i = 0; i < 4; i++)
            af[i] = *(const v8bf*)&As[(wm * 64 + i * 16 + m16) * 40 + quad * 8];
        #pragma unroll
        for (int j = 0; j < 4; j++)
            bf[j] = *(const v8bf*)&Bs[(wn * 64 + j * 16 + m16) * 40 + quad * 8];
        #pragma unroll
        for (int i = 0; i < 4; i++)
            #pragma unroll
            for (int j = 0; j < 4; j++)
                acc[i][j] = __builtin_amdgcn_mfma_f32_16x16x32_bf16(af[i], bf[j], acc[i][j], 0, 0, 0);
        __syncthreads();
    }

    // epilogue: D[row=quad*4+r][col=m16]  (verified C/D layout)
    #pragma unroll
    for (int j = 0; j < 4; j++) {
        int col = n0 + wn * 64 + j * 16 + m16;
        float bi = bias ? bias[col] : 0.f;
        #pragma unroll
        for (int i = 0; i < 4; i++) {
            int rowb = m0 + wm * 64 + i * 16 + quad * 4;
            #pragma unroll
            for (int r = 0; r < 4; r++) {
                float v = acc[i][j][r] + bi;
                size_t off = (size_t)(rowb + r) * N + col;
                if (Cf) Cf[off] = v;
                else    Cb[off] = f2bf(v);
            }
        }
    }
}

// ---------------- per-(b,col) max over n of qkv_m -> 1/(1e-6+max) ----------------
__global__ void k_colmax(const unsigned short* __restrict__ qm, float* __restrict__ invsc) {
    int b = blockIdx.x;
    int c = blockIdx.y * 256 + threadIdx.x;
    const unsigned short* p = qm + (size_t)b * NSEQ * QKV3 + c;
    float mx = -1e30f;
    for (int i = 0; i < NSEQ; i++) mx = fmaxf(mx, bf2f(p[(size_t)i * QKV3]));
    invsc[b * QKV3 + c] = 1.f / (1e-6f + mx);
}

// ---------------- build attention operands ----------------
// QQ = q*qm_norm*SCALE, KK = k*km_norm (row-major [b,h,i,d]); VVt = v*vm_norm, VMt = vm_norm
// (transposed [b,h,d,i], i padded to 512 with zeros -> uniform K-loop in attention).
__global__ __launch_bounds__(256) void k_build(const unsigned short* __restrict__ qkv,
                                               const unsigned short* __restrict__ qm,
                                               const float* __restrict__ invsc,
                                               unsigned short* __restrict__ QQ,
                                               unsigned short* __restrict__ KK,
                                               unsigned short* __restrict__ VVt,
                                               unsigned short* __restrict__ VMt) {
    __shared__ unsigned short tv[64][72];
    __shared__ unsigned short tm[64][72];
    int tid = threadIdx.x;
    int dd = tid & 63, il = tid >> 6;
    int it = blockIdx.x, h = blockIdx.y, b = blockIdx.z;
    int i0 = it * 64;
    size_t bh = (size_t)(b * HEADS_ + h);
    int c = h * HD + dd;
    float invq = invsc[b * QKV3 + c] * 0.125f;   // fold softmax scale 1/sqrt(64)
    float invk = invsc[b * QKV3 + 512 + c];
    float invv = invsc[b * QKV3 + 1024 + c];
    #pragma unroll 4
    for (int p = 0; p < 16; p++) {
        int li = p * 4 + il;
        int i = i0 + li;
        unsigned short oq = 0, ok = 0, ov = 0, om = 0;
        if (i < NSEQ) {
            size_t base = ((size_t)(b * NSEQ + i)) * QKV3 + c;
            float q  = bf2f(qkv[base]),        qv = bf2f(qm[base]);
            float kk = bf2f(qkv[base + 512]),  kv = bf2f(qm[base + 512]);
            float vv = bf2f(qkv[base + 1024]), vm = bf2f(qm[base + 1024]);
            oq = f2bf(q * qv * invq);
            ok = f2bf(kk * kv * invk);
            float vmn = vm * invv;
            ov = f2bf(vv * vmn);
            om = f2bf(vmn);
        }
        QQ[(bh * NPAD + i) * HD + dd] = oq;
        KK[(bh * NPAD + i) * HD + dd] = ok;
        tv[li][dd] = ov;
        tm[li][dd] = om;
    }
    __syncthreads();
    #pragma unroll 4
    for (int p = 0; p < 16; p++) {
        int dr = p * 4 + il;
        VVt[(bh * HD + dr) * NPAD + i0 + dd] = tv[dd][dr];
        VMt[(bh * HD + dr) * NPAD + i0 + dd] = tm[dd][dr];
    }
}

// ---------------- fused flash attention: online softmax, no score buffer ----------------
// 4 independent waves per block; each wave owns 16 query rows of one (b,h).
// Per 32-key chunk: QK^T in C-layout regs -> per-row max via 16-lane shfl (row group =
// fixed quad) -> online rescale of O/M accumulators -> unnormalized exp P (bf16) through
// a 1.25KB per-wave LDS tile (C-layout -> A-layout transform, intra-wave so no barrier)
// -> P@VV and P@VM with B-frags straight from transposed VVt/VMt. l is kept as a per-lane
// partial (alpha-rescaled; linear => exact) and reduced once at the end.
__global__ __launch_bounds__(256, 4) void k_attn(const unsigned short* __restrict__ QQ,
                                                 const unsigned short* __restrict__ KK,
                                                 const unsigned short* __restrict__ VVt,
                                                 const unsigned short* __restrict__ VMt,
                                                 const float* __restrict__ upd,
                                                 float* __restrict__ OUT1,
                                                 float* __restrict__ M1) {
    __shared__ __align__(16) unsigned short P[4][16 * 40];   // rows padded to 40 el (80 B, 16B-aligned reads)
    int tid = threadIdx.x;
    int w = tid >> 6, lane = tid & 63;
    int quad = lane >> 4, m16 = lane & 15;
    int b = blockIdx.z, h = blockIdx.y;
    int q0 = blockIdx.x * 64 + w * 16;
    size_t bh = (size_t)(b * HEADS_ + h);

    // Q A-frags (A[m=lane&15][k=quad*8+j]), rows >= NSEQ are zero in QQ (harmless)
    const unsigned short* qbase = &QQ[(bh * NPAD + q0 + m16) * HD];
    v8bf aq0 = *(const v8bf*)&qbase[quad * 8];
    v8bf aq1 = *(const v8bf*)&qbase[32 + quad * 8];

    v4f vacc[4], macc[4];
    #pragma unroll
    for (int dt = 0; dt < 4; dt++) {
        vacc[dt] = (v4f){0.f, 0.f, 0.f, 0.f};
        macc[dt] = (v4f){0.f, 0.f, 0.f, 0.f};
    }
    float mrun[4], lrun[4];
    #pragma unroll
    for (int r = 0; r < 4; r++) { mrun[r] = -1e30f; lrun[r] = 0.f; }

    unsigned short* Pw = &P[w][0];

    for (int ic = 0; ic < 16; ++ic) {
        int i0 = ic * 32;
        // K B-frags from global (L2-resident), two 16-key tiles
        const unsigned short* kb = &KK[(bh * NPAD + i0 + m16) * HD];
        v8bf k00 = *(const v8bf*)&kb[quad * 8];
        v8bf k01 = *(const v8bf*)&kb[32 + quad * 8];
        v8bf k10 = *(const v8bf*)&kb[16 * HD + quad * 8];
        v8bf k11 = *(const v8bf*)&kb[16 * HD + 32 + quad * 8];

        v4f s0 = (v4f){0.f, 0.f, 0.f, 0.f};
        v4f s1 = (v4f){0.f, 0.f, 0.f, 0.f};
        s0 = __builtin_amdgcn_mfma_f32_16x16x32_bf16(aq0, k00, s0, 0, 0, 0);
        s0 = __builtin_amdgcn_mfma_f32_16x16x32_bf16(aq1, k01, s0, 0, 0, 0);
        s1 = __builtin_amdgcn_mfma_f32_16x16x32_bf16(aq0, k10, s1, 0, 0, 0);
        s1 = __builtin_amdgcn_mfma_f32_16x16x32_bf16(aq1, k11, s1, 0, 0, 0);

        if (i0 + 32 > NSEQ) {                 // uniform branch, last chunk only
            bool x0 = (i0 + m16) >= NSEQ;      // C-layout: col = m16
            bool x1 = (i0 + 16 + m16) >= NSEQ;
            #pragma unroll
            for (int r = 0; r < 4; r++) {
                if (x0) s0[r] = -1e30f;
                if (x1) s1[r] = -1e30f;
            }
        }

        // per-row (quad*4+r) online-softmax update; reduction within 16-lane row group
        float al[4];
        #pragma unroll
        for (int r = 0; r < 4; r++) {
            float mx = fmaxf(s0[r], s1[r]);
            mx = fmaxf(mx, __shfl_xor(mx, 1));
            mx = fmaxf(mx, __shfl_xor(mx, 2));
            mx = fmaxf(mx, __shfl_xor(mx, 4));
            mx = fmaxf(mx, __shfl_xor(mx, 8));
            float mn = fmaxf(mrun[r], mx);
            al[r] = __expf(mrun[r] - mn);
            mrun[r] = mn;
        }
        unsigned short p0[4], p1[4];
        #pragma unroll
        for (int r = 0; r < 4; r++) {
            float e0 = __expf(s0[r] - mrun[r]);
            float e1 = __expf(s1[r] - mrun[r]);
            p0[r] = f2bf(e0);
            p1[r] = f2bf(e1);
            lrun[r] = lrun[r] * al[r] + (e0 + e1);   // per-lane partial
        }
        #pragma unroll
        for (int dt = 0; dt < 4; dt++)
            #pragma unroll
            for (int r = 0; r < 4; r++) {
                vacc[dt][r] *= al[r];
                macc[dt][r] *= al[r];
            }

        // P: C-layout -> LDS -> A-layout (intra-wave, compiler inserts lgkmcnt)
        #pragma unroll
        for (int r = 0; r < 4; r++) {
            Pw[(quad * 4 + r) * 40 + m16] = p0[r];
            Pw[(quad * 4 + r) * 40 + 16 + m16] = p1[r];
        }
        v8bf ap = *(const v8bf*)&Pw[m16 * 40 + quad * 8];

        // PV: B-frags from transposed V/VM (cols >= NSEQ are zero)
        #pragma unroll
        for (int dt = 0; dt < 4; dt++) {
            const unsigned short* vb = &VVt[(bh * HD + dt * 16 + m16) * NPAD + i0];
            const unsigned short* mb = &VMt[(bh * HD + dt * 16 + m16) * NPAD + i0];
            v8bf bv = *(const v8bf*)&vb[quad * 8];
            v8bf bm = *(const v8bf*)&mb[quad * 8];
            vacc[dt] = __builtin_amdgcn_mfma_f32_16x16x32_bf16(ap, bv, vacc[dt], 0, 0, 0);
            macc[dt] = __builtin_amdgcn_mfma_f32_16x16x32_bf16(ap, bm, macc[dt], 0, 0, 0);
        }
    }

    // final l reduction + normalized, gated outputs
    float inv[4];
    #pragma unroll
    for (int r = 0; r < 4; r++) {
        float s = lrun[r];
        s += __shfl_xor(s, 1);
        s += __shfl_xor(s, 2);
        s += __shfl_xor(s, 4);
        s += __shfl_xor(s, 8);
        inv[r] = 1.f / s;
    }
    #pragma unroll
    for (int r = 0; r < 4; r++) {
        int iq = q0 + quad * 4 + r;
        if (iq < NSEQ) {
            float u = upd[b * NSEQ + iq] * inv[r];
            size_t off = ((size_t)(b * NSEQ + iq)) * DIM + h * HD + m16;
            #pragma unroll
            for (int dt = 0; dt < 4; dt++) {
                OUT1[off + dt * 16] = vacc[dt][r] * u;
                M1[off + dt * 16]   = macc[dt][r] * u;
            }
        }
    }
}

// ---------------- overlap blending + row means (fp32), outputs bf16 GEMM inputs --------
__global__ __launch_bounds__(256) void k_blend(const float* __restrict__ O1,
                                               const float* __restrict__ Mm,
                                               const float* __restrict__ upd,
                                               unsigned short* __restrict__ O2,
                                               unsigned short* __restrict__ M2,
                                               float* __restrict__ mm) {
    int blk = blockIdx.x;
    int b = blk / NSEQ, i = blk - b * NSEQ;
    int tid = threadIdx.x;
    size_t rb = (size_t)blk * DIM;
    int ns = 0;
    size_t src[4];
    float wgt = 0.f;
    if (i >= 1) {
        wgt = 0.25f * (1.f - upd[blk]);
        if (wgt != 0.f) {
            if (i <= 256) {                       // grid row <- pooled(tail), padded pool
                int g = i - 1, gy = g >> 4, gx = g & 15;
                #pragma unroll
                for (int dy = 0; dy < 2; dy++)
                    #pragma unroll
                    for (int dx = 0; dx < 2; dx++) {
                        int sy = gy - 1 + dy, sx = gx - 1 + dx;
                        if (sy >= 0 && sy < 15 && sx >= 0 && sx < 15)
                            src[ns++] = ((size_t)(b * NSEQ + 257 + sy * 15 + sx)) * DIM;
                    }
            } else {                              // tail row <- pooled(grid), stride-1 2x2
                int t = i - 257, ty = t / 15, tx = t - ty * 15;
                #pragma unroll
                for (int dy = 0; dy < 2; dy++)
                    #pragma unroll
                    for (int dx = 0; dx < 2; dx++)
                        src[ns++] = ((size_t)(b * NSEQ + 1 + (ty + dy) * 16 + (tx + dx))) * DIM;
            }
        }
    }
    float msum = 0.f;
    for (int c = tid; c < DIM; c += 256) {
        float o = O1[rb + c], m = Mm[rb + c];
        float ao = 0.f, am = 0.f;
        for (int s = 0; s < ns; s++) { ao += O1[src[s] + c]; am += Mm[src[s] + c]; }
        o += wgt * ao;
        m += wgt * am;
        O2[rb + c] = f2bf(o);
        M2[rb + c] = f2bf(m);
        msum += m;
    }
    #pragma unroll
    for (int off = 32; off; off >>= 1) msum += __shfl_xor(msum, off);
    __shared__ float red[4];
    if ((tid & 63) == 0) red[tid >> 6] = msum;
    __syncthreads();
    if (tid == 0 && i >= 1)
        mm[b * 481 + i - 1] = (red[0] + red[1] + red[2] + red[3]) * (1.f / 512.f);
}

// ---------------- nearest-neighbor inter map ----------------
__global__ void k_inter(const float* __restrict__ mm, float* __restrict__ dst) {
    int idx = blockIdx.x * 256 + threadIdx.x;
    int b = idx >> 16, rem = idx & 65535;
    int y = rem >> 8, x = rem & 255;
    const float* mb = mm + b * 481;
    float v = mb[((y >> 4) << 4) + (x >> 4)];
    if (y >= 8 && y < 248 && x >= 8 && x < 248)
        v = 0.5f * (v + mb[256 + ((y - 8) >> 4) * 15 + ((x - 8) >> 4)]);
    dst[idx] = v;
}

// ---------------- driver ----------------
extern "C" void kernel_launch(void* const* d_in, const int* in_sizes, int n_in,
                              void* d_out, int out_size, void* d_ws, size_t ws_size,
                              hipStream_t stream) {
    const float* x    = (const float*)d_in[0];
    const float* mask = (const float*)d_in[1];
    const float* Wqkv = (const float*)d_in[2];
    const float* Wout = (const float*)d_in[3];
    const float* bout = (const float*)d_in[4];
    float* out = (float*)d_out;

    char* ws = (char*)d_ws;
    size_t o = 0;
    auto alloc = [&](size_t bytes) -> char* {
        char* r = ws + o;
        o += (bytes + 255) & ~(size_t)255;
        return r;
    };
    unsigned short* xb    = (unsigned short*)alloc((size_t)MROWS * DIM * 2);
    unsigned short* maskb = (unsigned short*)alloc((size_t)MROWS * DIM * 2);
    unsigned short* Wb    = (unsigned short*)alloc((size_t)QKV3 * DIM * 2);
    unsigned short* Wab   = (unsigned short*)alloc((size_t)QKV3 * DIM * 2);
    unsigned short* Wob   = (unsigned short*)alloc((size_t)DIM * DIM * 2);
    unsigned short* Woab  = (unsigned short*)alloc((size_t)DIM * DIM * 2);
    unsigned short* qkvb  = (unsigned short*)alloc((size_t)MROWS * QKV3 * 2);
    unsigned short* qkvmb = (unsigned short*)alloc((size_t)MROWS * QKV3 * 2);
    float* upd  = (float*)alloc((size_t)MROWS * 4);
    float* invs = (float*)alloc((size_t)B_ * QKV3 * 4);
    float* mm   = (float*)alloc((size_t)B_ * 481 * 4);
    unsigned short* QQ  = (unsigned short*)alloc((size_t)B_ * HEADS_ * NPAD * HD * 2);
    unsigned short* KK  = (unsigned short*)alloc((size_t)B_ * HEADS_ * NPAD * HD * 2);
    unsigned short* VVt = (unsigned short*)alloc((size_t)B_ * HEADS_ * NPAD * HD * 2);
    unsigned short* VMt = (unsigned short*)alloc((size_t)B_ * HEADS_ * NPAD * HD * 2);
    // aliases over dead buffers (qkv dead after k_build; xb/maskb dead after GEMM1)
    float* OUT1 = (float*)qkvb;
    float* M1p  = (float*)qkvmb;
    unsigned short* O2 = xb;
    unsigned short* M2 = maskb;

    // conversions + gate
    k_cvt<<<(MROWS * DIM / 4) / 256, 256, 0, stream>>>(x, xb, MROWS * DIM / 4);
    k_cvt<<<(MROWS * DIM / 4) / 256, 256, 0, stream>>>(mask, maskb, MROWS * DIM / 4);
    k_cvtabs<<<(QKV3 * DIM / 4) / 256, 256, 0, stream>>>(Wqkv, Wb, Wab, QKV3 * DIM / 4);
    k_cvtabs<<<(DIM * DIM / 4) / 256, 256, 0, stream>>>(Wout, Wob, Woab, DIM * DIM / 4);
    k_upd<<<MROWS / 4, 256, 0, stream>>>(mask, upd);

    // qkv projections (bf16 out)
    dim3 g1(QKV3 / 128, MROWS / 128);
    k_gemm<<<g1, 256, 0, stream>>>(xb, Wb, qkvb, nullptr, nullptr, QKV3, DIM);
    k_gemm<<<g1, 256, 0, stream>>>(maskb, Wab, qkvmb, nullptr, nullptr, QKV3, DIM);

    // normalization scales + operand build
    k_colmax<<<dim3(B_, QKV3 / 256), 256, 0, stream>>>(qkvmb, invs);
    k_build<<<dim3(8, HEADS_, B_), 256, 0, stream>>>(qkvb, qkvmb, invs, QQ, KK, VVt, VMt);

    // fused flash attention (writes gated OUT1 / M1)
    k_attn<<<dim3(8, HEADS_, B_), 256, 0, stream>>>(QQ, KK, VVt, VMt, upd, OUT1, M1p);

    // overlap blend + row means, inter map
    k_blend<<<MROWS, 256, 0, stream>>>(OUT1, M1p, upd, O2, M2, mm);
    k_inter<<<(B_ * 65536) / 256, 256, 0, stream>>>(mm, out + (size_t)2 * MROWS * DIM);

    // output projections (f32 out into d_out)
    dim3 g2(DIM / 128, MROWS / 128);
    k_gemm<<<g2, 256, 0, stream>>>(O2, Wob, nullptr, out, bout, DIM, DIM);
    k_gemm<<<g2, 256, 0, stream>>>(M2, Woab, nullptr, out + (size_t)MROWS * DIM, nullptr, DIM, DIM);
}

// Round 3
// 867.027 us; speedup vs baseline: 1.4055x; 1.2551x over previous
//
#include <hip/hip_runtime.h>

// ---- problem constants ----
#define B_      64
#define NSEQ    482
#define DIM     512
#define HEADS_  8
#define HD      64
#define QKV3    1536
#define NPAD    512            // padded sequence length for attention tensors
#define MROWS   (B_ * NSEQ)    // 30848 = 241 * 128

typedef __bf16 v8bf __attribute__((ext_vector_type(8)));
typedef float  v4f  __attribute__((ext_vector_type(4)));

typedef __attribute__((address_space(1))) const unsigned short gu16;
typedef __attribute__((address_space(3))) unsigned short lu16;

__device__ __forceinline__ unsigned short f2bf(float f) {
    unsigned u = __float_as_uint(f);
    u += 0x7fffu + ((u >> 16) & 1u);           // RNE
    return (unsigned short)(u >> 16);
}
__device__ __forceinline__ float bf2f(unsigned short h) {
    return __uint_as_float(((unsigned)h) << 16);
}

// ---------------- conversions ----------------
__global__ void k_cvt(const float* __restrict__ s, unsigned short* __restrict__ d, int n4) {
    int i = blockIdx.x * 256 + threadIdx.x;
    if (i < n4) {
        float4 v = ((const float4*)s)[i];
        ushort4 o;
        o.x = f2bf(v.x); o.y = f2bf(v.y); o.z = f2bf(v.z); o.w = f2bf(v.w);
        ((ushort4*)d)[i] = o;
    }
}

__global__ void k_cvtabs(const float* __restrict__ s, unsigned short* __restrict__ d,
                         unsigned short* __restrict__ da, int n4) {
    int i = blockIdx.x * 256 + threadIdx.x;
    if (i < n4) {
        float4 v = ((const float4*)s)[i];
        ushort4 o, oa;
        o.x = f2bf(v.x); o.y = f2bf(v.y); o.z = f2bf(v.z); o.w = f2bf(v.w);
        oa.x = f2bf(fabsf(v.x)); oa.y = f2bf(fabsf(v.y));
        oa.z = f2bf(fabsf(v.z)); oa.w = f2bf(fabsf(v.w));
        ((ushort4*)d)[i] = o;
        ((ushort4*)da)[i] = oa;
    }
}

// ---------------- updated gate (fp32, exact) ----------------
__global__ void k_upd(const float* __restrict__ mask, float* __restrict__ upd) {
    int row = blockIdx.x * 4 + (threadIdx.x >> 6);
    int lane = threadIdx.x & 63;
    int i = row % NSEQ;
    float r;
    if (i == 0) {
        r = 1.f;
    } else {
        const float* p = mask + (size_t)row * DIM;
        float s = 0.f;
        #pragma unroll
        for (int j = 0; j < 8; j++) s += p[lane + 64 * j];
        #pragma unroll
        for (int off = 32; off; off >>= 1) s += __shfl_xor(s, off);
        r = (s > 0.f) ? 1.f : 0.f;     // mean>0 <=> sum>0
    }
    if (lane == 0) upd[row] = r;
}

// ---------------- generic bf16 GEMM: C[M,N] = A[M,K] @ B[N,K]^T (+bias) ----------------
// m97 structure: 128x128 tile, global_load_lds width=16 staging into unpadded
// 128x32 LDS tiles, 4 waves (2x2), 4x4 16x16x32 MFMA micro-tiles.
__global__ __launch_bounds__(256, 2) void k_gemm(const unsigned short* __restrict__ A,
                                                 const unsigned short* __restrict__ Bw,
                                                 unsigned short* __restrict__ Cb,
                                                 float* __restrict__ Cf,
                                                 const float* __restrict__ bias,
                                                 int N, int K) {
    __shared__ __align__(16) unsigned short As[128 * 32];
    __shared__ __align__(16) unsigned short Bs[128 * 32];
    int tid = threadIdx.x;
    int lane = tid & 63, w = tid >> 6;
    int wm = w & 1, wn = w >> 1;
    int quad = lane >> 4, m16 = lane & 15;
    int m0 = blockIdx.y * 128, n0 = blockIdx.x * 128;

    // staging: each wave fills rows [rr*64 + w*16, +16) ; lane l -> row +l/4, col (l&3)*8
    int srow = w * 16 + (lane >> 2);
    int scol = (lane & 3) * 8;
    const unsigned short* gA0 = &A[(size_t)(m0 + srow) * K + scol];
    const unsigned short* gA1 = &A[(size_t)(m0 + 64 + srow) * K + scol];
    const unsigned short* gB0 = &Bw[(size_t)(n0 + srow) * K + scol];
    const unsigned short* gB1 = &Bw[(size_t)(n0 + 64 + srow) * K + scol];
    lu16* lA0 = (lu16*)&As[w * 512];            // HW adds lane*16B
    lu16* lA1 = (lu16*)&As[2048 + w * 512];
    lu16* lB0 = (lu16*)&Bs[w * 512];
    lu16* lB1 = (lu16*)&Bs[2048 + w * 512];

    v4f acc[4][4];
    #pragma unroll
    for (int i = 0; i < 4; i++)
        #pragma unroll
        for (int j = 0; j < 4; j++) acc[i][j] = (v4f){0.f, 0.f, 0.f, 0.f};

    for (int k0 = 0; k0 < K; k0 += 32) {
        __builtin_amdgcn_global_load_lds((gu16*)(gA0 + k0), lA0, 16, 0, 0);
        __builtin_amdgcn_global_load_lds((gu16*)(gA1 + k0), lA1, 16, 0, 0);
        __builtin_amdgcn_global_load_lds((gu16*)(gB0 + k0), lB0, 16, 0, 0);
        __builtin_amdgcn_global_load_lds((gu16*)(gB1 + k0), lB1, 16, 0, 0);
        __syncthreads();
        v8bf af[4], bf[4];
        #pragma unroll
        for (int i = 0; i < 4; i++)
            af[i] = *(const v8bf*)&As[(wm * 64 + i * 16 + m16) * 32 + quad * 8];
        #pragma unroll
        for (int j = 0; j < 4; j++)
            bf[j] = *(const v8bf*)&Bs[(wn * 64 + j * 16 + m16) * 32 + quad * 8];
        #pragma unroll
        for (int i = 0; i < 4; i++)
            #pragma unroll
            for (int j = 0; j < 4; j++)
                acc[i][j] = __builtin_amdgcn_mfma_f32_16x16x32_bf16(af[i], bf[j], acc[i][j], 0, 0, 0);
        __syncthreads();
    }

    // epilogue: D[row=quad*4+r][col=m16]  (verified C/D layout)
    #pragma unroll
    for (int j = 0; j < 4; j++) {
        int col = n0 + wn * 64 + j * 16 + m16;
        float bi = bias ? bias[col] : 0.f;
        #pragma unroll
        for (int i = 0; i < 4; i++) {
            int rowb = m0 + wm * 64 + i * 16 + quad * 4;
            #pragma unroll
            for (int r = 0; r < 4; r++) {
                float v = acc[i][j][r] + bi;
                size_t off = (size_t)(rowb + r) * N + col;
                if (Cf) Cf[off] = v;
                else    Cb[off] = f2bf(v);
            }
        }
    }
}

// ---------------- per-(b,col) max over n of qkv_m -> 1/(1e-6+max) ----------------
__global__ void k_colmax(const unsigned short* __restrict__ qm, float* __restrict__ invsc) {
    int b = blockIdx.x;
    int c = blockIdx.y * 256 + threadIdx.x;
    const unsigned short* p = qm + (size_t)b * NSEQ * QKV3 + c;
    float mx = -1e30f;
    for (int i = 0; i < NSEQ; i++) mx = fmaxf(mx, bf2f(p[(size_t)i * QKV3]));
    invsc[b * QKV3 + c] = 1.f / (1e-6f + mx);
}

// ---------------- build attention operands ----------------
// QQ = q*qm_norm*SCALE, KK = k*km_norm (row-major [b,h,i,d]); VVt = v*vm_norm, VMt = vm_norm
// (transposed [b,h,d,i], i padded to 512 with zeros -> uniform K-loop in attention).
__global__ __launch_bounds__(256) void k_build(const unsigned short* __restrict__ qkv,
                                               const unsigned short* __restrict__ qm,
                                               const float* __restrict__ invsc,
                                               unsigned short* __restrict__ QQ,
                                               unsigned short* __restrict__ KK,
                                               unsigned short* __restrict__ VVt,
                                               unsigned short* __restrict__ VMt) {
    __shared__ unsigned short tv[64][72];
    __shared__ unsigned short tm[64][72];
    int tid = threadIdx.x;
    int dd = tid & 63, il = tid >> 6;
    int it = blockIdx.x, h = blockIdx.y, b = blockIdx.z;
    int i0 = it * 64;
    size_t bh = (size_t)(b * HEADS_ + h);
    int c = h * HD + dd;
    float invq = invsc[b * QKV3 + c] * 0.125f;   // fold softmax scale 1/sqrt(64)
    float invk = invsc[b * QKV3 + 512 + c];
    float invv = invsc[b * QKV3 + 1024 + c];
    #pragma unroll 4
    for (int p = 0; p < 16; p++) {
        int li = p * 4 + il;
        int i = i0 + li;
        unsigned short oq = 0, ok = 0, ov = 0, om = 0;
        if (i < NSEQ) {
            size_t base = ((size_t)(b * NSEQ + i)) * QKV3 + c;
            float q  = bf2f(qkv[base]),        qv = bf2f(qm[base]);
            float kk = bf2f(qkv[base + 512]),  kv = bf2f(qm[base + 512]);
            float vv = bf2f(qkv[base + 1024]), vm = bf2f(qm[base + 1024]);
            oq = f2bf(q * qv * invq);
            ok = f2bf(kk * kv * invk);
            float vmn = vm * invv;
            ov = f2bf(vv * vmn);
            om = f2bf(vmn);
        }
        QQ[(bh * NPAD + i) * HD + dd] = oq;
        KK[(bh * NPAD + i) * HD + dd] = ok;
        tv[li][dd] = ov;
        tm[li][dd] = om;
    }
    __syncthreads();
    #pragma unroll 4
    for (int p = 0; p < 16; p++) {
        int dr = p * 4 + il;
        VVt[(bh * HD + dr) * NPAD + i0 + dd] = tv[dd][dr];
        VMt[(bh * HD + dr) * NPAD + i0 + dd] = tm[dd][dr];
    }
}

// ---------------- fused flash attention, v3 ----------------
// Block = 4 waves x 32 query rows = 128 queries of one (b,h); 4 blocks per bh.
// Per 32-key chunk: K/V/M staged cooperatively into padded LDS (coalesced contiguous
// global loads, issued one chunk ahead in registers to hide L2 latency under compute).
// Each wave: 8 QK MFMAs -> online softmax (2 rowsets, 16-lane shfl groups) -> P via
// per-wave LDS tile (C->A layout, wave-ordered) -> 16 PV MFMAs from shared LDS V/M.
__global__ __launch_bounds__(256, 3) void k_attn(const unsigned short* __restrict__ QQ,
                                                 const unsigned short* __restrict__ KK,
                                                 const unsigned short* __restrict__ VVt,
                                                 const unsigned short* __restrict__ VMt,
                                                 const float* __restrict__ upd,
                                                 float* __restrict__ OUT1,
                                                 float* __restrict__ M1) {
    __shared__ __align__(16) unsigned short Ks[32 * 72];     // [key][64d + 8 pad]
    __shared__ __align__(16) unsigned short Vs[64 * 40];     // [d][32key + 8 pad]
    __shared__ __align__(16) unsigned short Ms[64 * 40];
    __shared__ __align__(16) unsigned short Ps[4][32 * 40];  // per-wave P [32q][32k + 8]

    int tid = threadIdx.x;
    int w = tid >> 6, lane = tid & 63;
    int quad = lane >> 4, m16 = lane & 15;
    int b = blockIdx.z, h = blockIdx.y;
    int q0 = blockIdx.x * 128 + w * 32;
    size_t bh = (size_t)(b * HEADS_ + h);

    // Q A-frags for 2 rowsets (rows >= NSEQ are zero in QQ)
    v8bf aq[2][2];
    #pragma unroll
    for (int s = 0; s < 2; s++) {
        const unsigned short* qb = &QQ[(bh * NPAD + q0 + s * 16 + m16) * HD];
        aq[s][0] = *(const v8bf*)&qb[quad * 8];
        aq[s][1] = *(const v8bf*)&qb[32 + quad * 8];
    }

    v4f vacc[2][4], macc[2][4];
    #pragma unroll
    for (int s = 0; s < 2; s++)
        #pragma unroll
        for (int dt = 0; dt < 4; dt++) {
            vacc[s][dt] = (v4f){0.f, 0.f, 0.f, 0.f};
            macc[s][dt] = (v4f){0.f, 0.f, 0.f, 0.f};
        }
    float mrun[2][4], lrun[2][4];
    #pragma unroll
    for (int s = 0; s < 2; s++)
        #pragma unroll
        for (int r = 0; r < 4; r++) { mrun[s][r] = -1e30f; lrun[s][r] = 0.f; }

    // staging pointers (chunk-invariant parts)
    const unsigned short* gK = &KK[bh * NPAD * HD + tid * 8];                       // + ic*32*HD
    const unsigned short* gV = &VVt[(bh * HD + (tid >> 2)) * NPAD + (tid & 3) * 8]; // + ic*32
    const unsigned short* gM = &VMt[(bh * HD + (tid >> 2)) * NPAD + (tid & 3) * 8];
    unsigned short* wK = &Ks[(tid >> 3) * 72 + (tid & 7) * 8];
    unsigned short* wV = &Vs[(tid >> 2) * 40 + (tid & 3) * 8];
    unsigned short* wM = &Ms[(tid >> 2) * 40 + (tid & 3) * 8];
    unsigned short* Pw = &Ps[w][0];

    int4 rk = *(const int4*)gK;          // prefetch chunk 0
    int4 rv = *(const int4*)gV;
    int4 rm = *(const int4*)gM;

    for (int ic = 0; ic < 16; ++ic) {
        if (ic) __syncthreads();         // all readers of chunk ic-1 done
        *(int4*)wK = rk;
        *(int4*)wV = rv;
        *(int4*)wM = rm;
        __syncthreads();                 // stage visible to all waves
        if (ic < 15) {                   // prefetch chunk ic+1; latency hides under compute
            rk = *(const int4*)(gK + (ic + 1) * 32 * HD);
            rv = *(const int4*)(gV + (ic + 1) * 32);
            rm = *(const int4*)(gM + (ic + 1) * 32);
        }

        // QK^T: S[rowset][keytile]
        v8bf kf[2][2];
        #pragma unroll
        for (int t = 0; t < 2; t++) {
            kf[t][0] = *(const v8bf*)&Ks[(t * 16 + m16) * 72 + quad * 8];
            kf[t][1] = *(const v8bf*)&Ks[(t * 16 + m16) * 72 + 32 + quad * 8];
        }
        v4f S[2][2];
        #pragma unroll
        for (int s = 0; s < 2; s++)
            #pragma unroll
            for (int t = 0; t < 2; t++) {
                v4f a = (v4f){0.f, 0.f, 0.f, 0.f};
                a = __builtin_amdgcn_mfma_f32_16x16x32_bf16(aq[s][0], kf[t][0], a, 0, 0, 0);
                a = __builtin_amdgcn_mfma_f32_16x16x32_bf16(aq[s][1], kf[t][1], a, 0, 0, 0);
                S[s][t] = a;
            }

        int i0 = ic * 32;
        if (i0 + 32 > NSEQ) {            // uniform branch, last chunk only
            bool x0 = (i0 + m16) >= NSEQ;       // C-layout: col = m16
            bool x1 = (i0 + 16 + m16) >= NSEQ;
            #pragma unroll
            for (int s = 0; s < 2; s++)
                #pragma unroll
                for (int r = 0; r < 4; r++) {
                    if (x0) S[s][0][r] = -1e30f;
                    if (x1) S[s][1][r] = -1e30f;
                }
        }

        // online softmax per row (rowset s, row quad*4+r), 16-lane reduction groups
        #pragma unroll
        for (int s = 0; s < 2; s++)
            #pragma unroll
            for (int r = 0; r < 4; r++) {
                float mx = fmaxf(S[s][0][r], S[s][1][r]);
                mx = fmaxf(mx, __shfl_xor(mx, 1));
                mx = fmaxf(mx, __shfl_xor(mx, 2));
                mx = fmaxf(mx, __shfl_xor(mx, 4));
                mx = fmaxf(mx, __shfl_xor(mx, 8));
                float mn = fmaxf(mrun[s][r], mx);
                float a = __expf(mrun[s][r] - mn);
                mrun[s][r] = mn;
                float e0 = __expf(S[s][0][r] - mn);
                float e1 = __expf(S[s][1][r] - mn);
                lrun[s][r] = lrun[s][r] * a + (e0 + e1);   // per-lane partial (exact)
                Pw[(s * 16 + quad * 4 + r) * 40 + m16] = f2bf(e0);
                Pw[(s * 16 + quad * 4 + r) * 40 + 16 + m16] = f2bf(e1);
                #pragma unroll
                for (int dt = 0; dt < 4; dt++) {
                    vacc[s][dt][r] *= a;
                    macc[s][dt][r] *= a;
                }
            }

        // P: C-layout -> LDS -> A-layout (intra-wave, wave-ordered)
        v8bf ap[2];
        ap[0] = *(const v8bf*)&Pw[m16 * 40 + quad * 8];
        ap[1] = *(const v8bf*)&Pw[(16 + m16) * 40 + quad * 8];

        // PV from shared LDS V/M (B-frags identical across waves -> staged once)
        #pragma unroll
        for (int dt = 0; dt < 4; dt++) {
            v8bf bv = *(const v8bf*)&Vs[(dt * 16 + m16) * 40 + quad * 8];
            v8bf bm = *(const v8bf*)&Ms[(dt * 16 + m16) * 40 + quad * 8];
            #pragma unroll
            for (int s = 0; s < 2; s++) {
                vacc[s][dt] = __builtin_amdgcn_mfma_f32_16x16x32_bf16(ap[s], bv, vacc[s][dt], 0, 0, 0);
                macc[s][dt] = __builtin_amdgcn_mfma_f32_16x16x32_bf16(ap[s], bm, macc[s][dt], 0, 0, 0);
            }
        }
    }

    // final l reduction + normalized, gated outputs
    #pragma unroll
    for (int s = 0; s < 2; s++)
        #pragma unroll
        for (int r = 0; r < 4; r++) {
            float sum = lrun[s][r];
            sum += __shfl_xor(sum, 1);
            sum += __shfl_xor(sum, 2);
            sum += __shfl_xor(sum, 4);
            sum += __shfl_xor(sum, 8);
            float iv = 1.f / sum;
            int iq = q0 + s * 16 + quad * 4 + r;
            if (iq < NSEQ) {
                float u = upd[b * NSEQ + iq] * iv;
                size_t off = ((size_t)(b * NSEQ + iq)) * DIM + h * HD + m16;
                #pragma unroll
                for (int dt = 0; dt < 4; dt++) {
                    OUT1[off + dt * 16] = vacc[s][dt][r] * u;
                    M1[off + dt * 16]   = macc[s][dt][r] * u;
                }
            }
        }
}

// ---------------- overlap blending + row means (fp32), outputs bf16 GEMM inputs --------
__global__ __launch_bounds__(256) void k_blend(const float* __restrict__ O1,
                                               const float* __restrict__ Mm,
                                               const float* __restrict__ upd,
                                               unsigned short* __restrict__ O2,
                                               unsigned short* __restrict__ M2,
                                               float* __restrict__ mm) {
    int blk = blockIdx.x;
    int b = blk / NSEQ, i = blk - b * NSEQ;
    int tid = threadIdx.x;
    size_t rb = (size_t)blk * DIM;
    int ns = 0;
    size_t src[4];
    float wgt = 0.f;
    if (i >= 1) {
        wgt = 0.25f * (1.f - upd[blk]);
        if (wgt != 0.f) {
            if (i <= 256) {                       // grid row <- pooled(tail), padded pool
                int g = i - 1, gy = g >> 4, gx = g & 15;
                #pragma unroll
                for (int dy = 0; dy < 2; dy++)
                    #pragma unroll
                    for (int dx = 0; dx < 2; dx++) {
                        int sy = gy - 1 + dy, sx = gx - 1 + dx;
                        if (sy >= 0 && sy < 15 && sx >= 0 && sx < 15)
                            src[ns++] = ((size_t)(b * NSEQ + 257 + sy * 15 + sx)) * DIM;
                    }
            } else {                              // tail row <- pooled(grid), stride-1 2x2
                int t = i - 257, ty = t / 15, tx = t - ty * 15;
                #pragma unroll
                for (int dy = 0; dy < 2; dy++)
                    #pragma unroll
                    for (int dx = 0; dx < 2; dx++)
                        src[ns++] = ((size_t)(b * NSEQ + 1 + (ty + dy) * 16 + (tx + dx))) * DIM;
            }
        }
    }
    float msum = 0.f;
    for (int c = tid; c < DIM; c += 256) {
        float o = O1[rb + c], m = Mm[rb + c];
        float ao = 0.f, am = 0.f;
        for (int s = 0; s < ns; s++) { ao += O1[src[s] + c]; am += Mm[src[s] + c]; }
        o += wgt * ao;
        m += wgt * am;
        O2[rb + c] = f2bf(o);
        M2[rb + c] = f2bf(m);
        msum += m;
    }
    #pragma unroll
    for (int off = 32; off; off >>= 1) msum += __shfl_xor(msum, off);
    __shared__ float red[4];
    if ((tid & 63) == 0) red[tid >> 6] = msum;
    __syncthreads();
    if (tid == 0 && i >= 1)
        mm[b * 481 + i - 1] = (red[0] + red[1] + red[2] + red[3]) * (1.f / 512.f);
}

// ---------------- nearest-neighbor inter map ----------------
__global__ void k_inter(const float* __restrict__ mm, float* __restrict__ dst) {
    int idx = blockIdx.x * 256 + threadIdx.x;
    int b = idx >> 16, rem = idx & 65535;
    int y = rem >> 8, x = rem & 255;
    const float* mb = mm + b * 481;
    float v = mb[((y >> 4) << 4) + (x >> 4)];
    if (y >= 8 && y < 248 && x >= 8 && x < 248)
        v = 0.5f * (v + mb[256 + ((y - 8) >> 4) * 15 + ((x - 8) >> 4)]);
    dst[idx] = v;
}

// ---------------- driver ----------------
extern "C" void kernel_launch(void* const* d_in, const int* in_sizes, int n_in,
                              void* d_out, int out_size, void* d_ws, size_t ws_size,
                              hipStream_t stream) {
    const float* x    = (const float*)d_in[0];
    const float* mask = (const float*)d_in[1];
    const float* Wqkv = (const float*)d_in[2];
    const float* Wout = (const float*)d_in[3];
    const float* bout = (const float*)d_in[4];
    float* out = (float*)d_out;

    char* ws = (char*)d_ws;
    size_t o = 0;
    auto alloc = [&](size_t bytes) -> char* {
        char* r = ws + o;
        o += (bytes + 255) & ~(size_t)255;
        return r;
    };
    unsigned short* xb    = (unsigned short*)alloc((size_t)MROWS * DIM * 2);
    unsigned short* maskb = (unsigned short*)alloc((size_t)MROWS * DIM * 2);
    unsigned short* Wb    = (unsigned short*)alloc((size_t)QKV3 * DIM * 2);
    unsigned short* Wab   = (unsigned short*)alloc((size_t)QKV3 * DIM * 2);
    unsigned short* Wob   = (unsigned short*)alloc((size_t)DIM * DIM * 2);
    unsigned short* Woab  = (unsigned short*)alloc((size_t)DIM * DIM * 2);
    unsigned short* qkvb  = (unsigned short*)alloc((size_t)MROWS * QKV3 * 2);
    unsigned short* qkvmb = (unsigned short*)alloc((size_t)MROWS * QKV3 * 2);
    float* upd  = (float*)alloc((size_t)MROWS * 4);
    float* invs = (float*)alloc((size_t)B_ * QKV3 * 4);
    float* mm   = (float*)alloc((size_t)B_ * 481 * 4);
    unsigned short* QQ  = (unsigned short*)alloc((size_t)B_ * HEADS_ * NPAD * HD * 2);
    unsigned short* KK  = (unsigned short*)alloc((size_t)B_ * HEADS_ * NPAD * HD * 2);
    unsigned short* VVt = (unsigned short*)alloc((size_t)B_ * HEADS_ * NPAD * HD * 2);
    unsigned short* VMt = (unsigned short*)alloc((size_t)B_ * HEADS_ * NPAD * HD * 2);
    // aliases over dead buffers (qkv dead after k_build; xb/maskb dead after GEMM1)
    float* OUT1 = (float*)qkvb;
    float* M1p  = (float*)qkvmb;
    unsigned short* O2 = xb;
    unsigned short* M2 = maskb;

    // conversions + gate
    k_cvt<<<(MROWS * DIM / 4) / 256, 256, 0, stream>>>(x, xb, MROWS * DIM / 4);
    k_cvt<<<(MROWS * DIM / 4) / 256, 256, 0, stream>>>(mask, maskb, MROWS * DIM / 4);
    k_cvtabs<<<(QKV3 * DIM / 4) / 256, 256, 0, stream>>>(Wqkv, Wb, Wab, QKV3 * DIM / 4);
    k_cvtabs<<<(DIM * DIM / 4) / 256, 256, 0, stream>>>(Wout, Wob, Woab, DIM * DIM / 4);
    k_upd<<<MROWS / 4, 256, 0, stream>>>(mask, upd);

    // qkv projections (bf16 out)
    dim3 g1(QKV3 / 128, MROWS / 128);
    k_gemm<<<g1, 256, 0, stream>>>(xb, Wb, qkvb, nullptr, nullptr, QKV3, DIM);
    k_gemm<<<g1, 256, 0, stream>>>(maskb, Wab, qkvmb, nullptr, nullptr, QKV3, DIM);

    // normalization scales + operand build
    k_colmax<<<dim3(B_, QKV3 / 256), 256, 0, stream>>>(qkvmb, invs);
    k_build<<<dim3(8, HEADS_, B_), 256, 0, stream>>>(qkvb, qkvmb, invs, QQ, KK, VVt, VMt);

    // fused flash attention (writes gated OUT1 / M1); 128 queries/block
    k_attn<<<dim3(4, HEADS_, B_), 256, 0, stream>>>(QQ, KK, VVt, VMt, upd, OUT1, M1p);

    // overlap blend + row means, inter map
    k_blend<<<MROWS, 256, 0, stream>>>(OUT1, M1p, upd, O2, M2, mm);
    k_inter<<<(B_ * 65536) / 256, 256, 0, stream>>>(mm, out + (size_t)2 * MROWS * DIM);

    // output projections (f32 out into d_out)
    dim3 g2(DIM / 128, MROWS / 128);
    k_gemm<<<g2, 256, 0, stream>>>(O2, Wob, nullptr, out, bout, DIM, DIM);
    k_gemm<<<g2, 256, 0, stream>>>(M2, Woab, nullptr, out + (size_t)MROWS * DIM, nullptr, DIM, DIM);
}